// Round 12
// baseline (40.712 us; speedup 1.0000x reference)
//
#include <hip/hip_runtime.h>
#include <math.h>

// Sizes (fixed by the problem)
#define Bb 8
#define Tt 32
#define Hh 64
#define Ww 64
#define Cc 3
#define Ff 24
#define Uu 128

// Fast activations: |err| ~1e-6, threshold is 1.86e-4.
__device__ __forceinline__ float fast_sigmoid(float x) {
    float e = __builtin_amdgcn_exp2f(-1.442695040888963f * x);
    return __builtin_amdgcn_rcpf(1.f + e);
}
__device__ __forceinline__ float fast_tanh(float x) {
    float e = __builtin_amdgcn_exp2f(-2.885390081777927f * x);
    return 2.f * __builtin_amdgcn_rcpf(1.f + e) - 1.f;
}
__device__ __forceinline__ float rl(float v, int lane) {
    return __builtin_bit_cast(float,
        __builtin_amdgcn_readlane(__builtin_bit_cast(int, v), lane));
}

// ---------------------------------------------------------------------------
// Kernel 1: fused per-frame stats + analytic double-conv + global-avg-pool
// + input-part of gate preactivations. G layout is now GATE-TRANSPOSED:
// G[(t*8+b)*512 + u*4 + g]  (so the LSTM reads one b128 per unit).
// ---------------------------------------------------------------------------
__global__ void convfeat_kernel(const float* __restrict__ x,
                                const float* __restrict__ w1, const float* __restrict__ b1,
                                const float* __restrict__ w2, const float* __restrict__ b2,
                                const float* __restrict__ Wf, const float* __restrict__ bf,
                                const float* __restrict__ Wi, const float* __restrict__ bi,
                                const float* __restrict__ Wc, const float* __restrict__ bc,
                                const float* __restrict__ Wo, const float* __restrict__ bo,
                                float* __restrict__ G) {
    int n = blockIdx.x;                       // frame = b*T + t
    const float* xf = x + (size_t)n * (Hh * Ww * Cc);
    int tid  = threadIdx.x;                   // 0..255
    int row  = tid >> 2;
    int part = tid & 3;

    __shared__ float partial[256][3];
    __shared__ float rowsum[64][3];
    __shared__ float colv[64][12];
    __shared__ float st[75];                  // [c*25 + j]
    __shared__ float yst[24][9];
    __shared__ float feats[24];

    float s0 = 0.f, s1 = 0.f, s2 = 0.f;
    const float4* p4 = (const float4*)(xf + (row * Ww + part * 16) * Cc);
#pragma unroll
    for (int i = 0; i < 12; ++i) {
        float4 v = p4[i];
        int j = i * 4;
        float vv[4] = {v.x, v.y, v.z, v.w};
#pragma unroll
        for (int l = 0; l < 4; ++l) {
            int c = (j + l) % 3;
            if (c == 0) s0 += vv[l]; else if (c == 1) s1 += vv[l]; else s2 += vv[l];
        }
    }
    partial[tid][0] = s0; partial[tid][1] = s1; partial[tid][2] = s2;

    if (tid < 64) {
        int r = tid;
#pragma unroll
        for (int w4 = 0; w4 < 4; ++w4) {
            int w = (w4 < 2) ? w4 : 60 + w4;
#pragma unroll
            for (int c = 0; c < 3; ++c) colv[r][w4 * 3 + c] = xf[(r * Ww + w) * Cc + c];
        }
    }
    __syncthreads();

    if (part == 0) {
#pragma unroll
        for (int c = 0; c < 3; ++c)
            rowsum[row][c] = partial[tid][c] + partial[tid + 1][c]
                           + partial[tid + 2][c] + partial[tid + 3][c];
    }
    __syncthreads();

    if (tid < 3) {
        float t = 0.f;
        for (int r = 0; r < 64; ++r) t += rowsum[r][tid];
        st[tid * 25 + 0] = t;
    }
    if (tid >= 4 && tid < 16) {
        int k = tid - 4; int ri = k / 3, c = k % 3;
        int r = (ri < 2) ? ri : 60 + ri;
        st[c * 25 + 1 + ri] = rowsum[r][c];
    }
    if (tid >= 64 && tid < 76) {
        int k = tid - 64;
        float t = 0.f;
        for (int r = 0; r < 64; ++r) t += colv[r][k];
        int wi = k / 3, c = k % 3;
        st[c * 25 + 5 + wi] = t;
    }
    if (tid >= 128 && tid < 176) {
        int k = tid - 128; int pos = k / 3, c = k % 3;
        int ri = pos >> 2, wi = pos & 3;
        int r = (ri < 2) ? ri : 60 + ri;
        int w = (wi < 2) ? wi : 60 + wi;
        st[c * 25 + 9 + pos] = xf[(r * Ww + w) * Cc + c];
    }
    __syncthreads();

    if (tid < 24) {
        int f = tid;
        float Sy = 0, r0 = 0, r63 = 0, c0 = 0, c63 = 0, y00 = 0, y0W = 0, yH0 = 0, yHW = 0;
        for (int c = 0; c < 3; ++c) {
            const float* S = st + c * 25;
            float Sx = S[0];
            float rX[4] = {S[1], S[2], S[3], S[4]};
            float cX[4] = {S[5], S[6], S[7], S[8]};
            const float* X = S + 9;
            #define W1(p, q) w1[(((p) * 3 + (q)) * 3 + c) * 24 + f]
#pragma unroll
            for (int p = 0; p < 3; ++p)
#pragma unroll
                for (int q = 0; q < 3; ++q) {
                    float t = Sx;
                    if (p == 0) t -= rX[3];
                    if (p == 2) t -= rX[0];
                    if (q == 0) t -= cX[3];
                    if (q == 2) t -= cX[0];
                    if (p == 0 && q == 0) t += X[3 * 4 + 3];
                    if (p == 0 && q == 2) t += X[3 * 4 + 0];
                    if (p == 2 && q == 0) t += X[0 * 4 + 3];
                    if (p == 2 && q == 2) t += X[0 * 4 + 0];
                    Sy += W1(p, q) * t;
                }
#pragma unroll
            for (int q = 0; q < 3; ++q) {
                float Rr0  = rX[0] - ((q == 0) ? X[0 * 4 + 3] : 0.f) - ((q == 2) ? X[0 * 4 + 0] : 0.f);
                float Rr1  = rX[1] - ((q == 0) ? X[1 * 4 + 3] : 0.f) - ((q == 2) ? X[1 * 4 + 0] : 0.f);
                float Rr62 = rX[2] - ((q == 0) ? X[2 * 4 + 3] : 0.f) - ((q == 2) ? X[2 * 4 + 0] : 0.f);
                float Rr63 = rX[3] - ((q == 0) ? X[3 * 4 + 3] : 0.f) - ((q == 2) ? X[3 * 4 + 0] : 0.f);
                r0  += W1(1, q) * Rr0  + W1(2, q) * Rr1;
                r63 += W1(0, q) * Rr62 + W1(1, q) * Rr63;
            }
#pragma unroll
            for (int p = 0; p < 3; ++p) {
                float Rc0  = cX[0] - ((p == 0) ? X[3 * 4 + 0] : 0.f) - ((p == 2) ? X[0 * 4 + 0] : 0.f);
                float Rc1  = cX[1] - ((p == 0) ? X[3 * 4 + 1] : 0.f) - ((p == 2) ? X[0 * 4 + 1] : 0.f);
                float Rc62 = cX[2] - ((p == 0) ? X[3 * 4 + 2] : 0.f) - ((p == 2) ? X[0 * 4 + 2] : 0.f);
                float Rc63 = cX[3] - ((p == 0) ? X[3 * 4 + 3] : 0.f) - ((p == 2) ? X[0 * 4 + 3] : 0.f);
                c0  += W1(p, 1) * Rc0  + W1(p, 2) * Rc1;
                c63 += W1(p, 0) * Rc62 + W1(p, 1) * Rc63;
            }
            y00 += W1(1, 1) * X[0 * 4 + 0] + W1(1, 2) * X[0 * 4 + 1]
                 + W1(2, 1) * X[1 * 4 + 0] + W1(2, 2) * X[1 * 4 + 1];
            y0W += W1(1, 0) * X[0 * 4 + 2] + W1(1, 1) * X[0 * 4 + 3]
                 + W1(2, 0) * X[1 * 4 + 2] + W1(2, 1) * X[1 * 4 + 3];
            yH0 += W1(0, 1) * X[2 * 4 + 0] + W1(0, 2) * X[2 * 4 + 1]
                 + W1(1, 1) * X[3 * 4 + 0] + W1(1, 2) * X[3 * 4 + 1];
            yHW += W1(0, 0) * X[2 * 4 + 2] + W1(0, 1) * X[2 * 4 + 3]
                 + W1(1, 0) * X[3 * 4 + 2] + W1(1, 1) * X[3 * 4 + 3];
            #undef W1
        }
        float bb = b1[f];
        yst[f][0] = Sy + 4096.f * bb;
        yst[f][1] = r0 + 64.f * bb;
        yst[f][2] = r63 + 64.f * bb;
        yst[f][3] = c0 + 64.f * bb;
        yst[f][4] = c63 + 64.f * bb;
        yst[f][5] = y00 + bb; yst[f][6] = y0W + bb;
        yst[f][7] = yH0 + bb; yst[f][8] = yHW + bb;
    }
    __syncthreads();

    if (tid < 24) {
        int g = tid;
        float acc = 0.f;
        for (int f = 0; f < 24; ++f) {
            float Sy = yst[f][0], rY0 = yst[f][1], rY63 = yst[f][2], cY0 = yst[f][3], cY63 = yst[f][4];
            float yc00 = yst[f][5], yc0W = yst[f][6], ycH0 = yst[f][7], ycHW = yst[f][8];
#pragma unroll
            for (int p = 0; p < 3; ++p)
#pragma unroll
                for (int q = 0; q < 3; ++q) {
                    float t = Sy;
                    if (p == 0) t -= rY63;
                    if (p == 2) t -= rY0;
                    if (q == 0) t -= cY63;
                    if (q == 2) t -= cY0;
                    if (p == 0 && q == 0) t += ycHW;
                    if (p == 0 && q == 2) t += ycH0;
                    if (p == 2 && q == 0) t += yc0W;
                    if (p == 2 && q == 2) t += yc00;
                    acc += w2[(((p * 3 + q) * 24 + f) * 24) + g] * t;
                }
        }
        feats[g] = b2[g] + acc * (1.f / 4096.f);
    }
    __syncthreads();

    // ---- fused gpre: 2 gate-columns per thread, GATE-TRANSPOSED store ----
    int b = n >> 5, t = n & 31;               // Tt = 32
    float* Gdst = G + ((size_t)(t * Bb + b)) * 512;
#pragma unroll
    for (int rep = 0; rep < 2; ++rep) {
        int col = tid + rep * 256;
        int gg = col >> 7, u = col & 127;
        const float* W    = (gg == 0) ? Wf : (gg == 1) ? Wi : (gg == 2) ? Wc : Wo;
        const float* bias = (gg == 0) ? bf : (gg == 1) ? bi : (gg == 2) ? bc : bo;
        float acc = bias[u];
#pragma unroll
        for (int k = 0; k < Ff; ++k) acc += feats[k] * W[k * Uu + u];
        Gdst[u * 4 + gg] = acc;               // [u][gate] layout
    }
}

// ---------------------------------------------------------------------------
// Kernel 2: LSTM recurrence — h distributed via v_readlane (NO LDS for h),
// partial exchange via b128 only.  512 threads, 8 waves, 1 block/CU (96 KB
// LDS guarantees it -> allocator's VGPR budget is 256; ~160 needed).
// Thread (q = w>>1, uc = (w&1)*64 + lane): ALL 4 gate-columns of unit uc,
// rows 32q..32q+32 -> 128 named weight floats + volatile keep-alive.
// Per step: phase A: 32x { readlane h -> 4 scalar FMA chains }, write one
// b128 partial; barrier; phase B (lanes<32): 4 b128 part reads + 1 b128 G
// read, activations, c/h update — unit 32q+lane, so next step's readlane
// sources are the wave's OWN lanes. part[] parity-double-buffered.
// DS per CU per step: ~48 b128 (vs ~230 instr before) — VALU becomes limiter.
// ---------------------------------------------------------------------------
__global__ __launch_bounds__(512)
__attribute__((amdgpu_waves_per_eu(2, 2)))
void lstm_kernel(
        const float* __restrict__ G,
        const float* __restrict__ Wf, const float* __restrict__ Wi,
        const float* __restrict__ Wc, const float* __restrict__ Wo,
        const float* __restrict__ out_w, const float* __restrict__ out_b,
        float* __restrict__ out) {
    int b   = blockIdx.x;
    int tid = threadIdx.x;
    int w   = tid >> 6;                       // wave 0..7
    int l   = tid & 63;                       // lane
    int q   = w >> 1;                         // row chunk 0..3 (rows 32q..+32)
    int uc  = ((w & 1) << 6) | l;             // this thread's unit-column

    // 128 named weight floats: rows 24+32q..+32 of column uc, all 4 gates.
    const float* Wfp = Wf + (size_t)(Ff + 32 * q) * Uu + uc;
    const float* Wip = Wi + (size_t)(Ff + 32 * q) * Uu + uc;
    const float* Wcp = Wc + (size_t)(Ff + 32 * q) * Uu + uc;
    const float* Wop = Wo + (size_t)(Ff + 32 * q) * Uu + uc;
#define LDWX(r) float wf##r = Wfp[(size_t)(r) * Uu]; \
                float wi##r = Wip[(size_t)(r) * Uu]; \
                float wc##r = Wcp[(size_t)(r) * Uu]; \
                float wo##r = Wop[(size_t)(r) * Uu]
    LDWX(0);  LDWX(1);  LDWX(2);  LDWX(3);  LDWX(4);  LDWX(5);  LDWX(6);  LDWX(7);
    LDWX(8);  LDWX(9);  LDWX(10); LDWX(11); LDWX(12); LDWX(13); LDWX(14); LDWX(15);
    LDWX(16); LDWX(17); LDWX(18); LDWX(19); LDWX(20); LDWX(21); LDWX(22); LDWX(23);
    LDWX(24); LDWX(25); LDWX(26); LDWX(27); LDWX(28); LDWX(29); LDWX(30); LDWX(31);
#undef LDWX
#define KAW(r) asm volatile("" : "+v"(wf##r), "+v"(wi##r), "+v"(wc##r), "+v"(wo##r))
    KAW(0);  KAW(1);  KAW(2);  KAW(3);  KAW(4);  KAW(5);  KAW(6);  KAW(7);
    KAW(8);  KAW(9);  KAW(10); KAW(11); KAW(12); KAW(13); KAW(14); KAW(15);
    KAW(16); KAW(17); KAW(18); KAW(19); KAW(20); KAW(21); KAW(22); KAW(23);
    KAW(24); KAW(25); KAW(26); KAW(27); KAW(28); KAW(29); KAW(30); KAW(31);
#undef KAW

    __shared__ __align__(16) float Gl[Tt][Uu * 4];     // 64 KB, [t][u*4+g]
    __shared__ __align__(16) float part[2][4][Uu][4];  // 16 KB
    __shared__ __align__(16) float hist[Tt][Uu];       // 16 KB

    // Prologue: copy G[b] slab (32x512) to LDS, coalesced.
    {
        int r  = tid >> 4;                    // 0..31 step
        int cc = (tid & 15) * 32;             // 0..480
        const float4* src = (const float4*)(G + ((size_t)(r * Bb + b)) * 512 + cc);
        float4* dst = (float4*)(&Gl[r][cc]);
#pragma unroll
        for (int i = 0; i < 8; ++i) dst[i] = src[i];
    }
    float hn = 0.f;                           // unit (32q+l)'s h, lanes 0..31
    float cs = 0.f;
    __syncthreads();

#pragma clang loop unroll(disable)
    for (int t = 0; t < Tt; ++t) {
        // ---- phase A: h via readlane (SGPR broadcast), 4 FMA chains ----
        float sf = 0.f, si = 0.f, sg = 0.f, so = 0.f;
#define STEPR(r) { float hr = rl(hn, r); \
        sf = fmaf(wf##r, hr, sf); si = fmaf(wi##r, hr, si); \
        sg = fmaf(wc##r, hr, sg); so = fmaf(wo##r, hr, so); }
        STEPR(0);  STEPR(1);  STEPR(2);  STEPR(3);
        STEPR(4);  STEPR(5);  STEPR(6);  STEPR(7);
        STEPR(8);  STEPR(9);  STEPR(10); STEPR(11);
        STEPR(12); STEPR(13); STEPR(14); STEPR(15);
        STEPR(16); STEPR(17); STEPR(18); STEPR(19);
        STEPR(20); STEPR(21); STEPR(22); STEPR(23);
        STEPR(24); STEPR(25); STEPR(26); STEPR(27);
        STEPR(28); STEPR(29); STEPR(30); STEPR(31);
#undef STEPR
        float4 pv; pv.x = sf; pv.y = si; pv.z = sg; pv.w = so;
        *(float4*)&part[t & 1][q][uc][0] = pv;
        __syncthreads();                      // the ONLY barrier per step

        // ---- phase B: lanes 0..31 update unit u = 32q+l (waves paired) ----
        if (l < 32) {
            int u = (q << 5) | l;
            const float4 p0 = *(const float4*)&part[t & 1][0][u][0];
            const float4 p1 = *(const float4*)&part[t & 1][1][u][0];
            const float4 p2 = *(const float4*)&part[t & 1][2][u][0];
            const float4 p3 = *(const float4*)&part[t & 1][3][u][0];
            const float4 gv = *(const float4*)&Gl[t][u * 4];
            float zf = p0.x + p1.x + p2.x + p3.x + gv.x;
            float zi = p0.y + p1.y + p2.y + p3.y + gv.y;
            float zg = p0.z + p1.z + p2.z + p3.z + gv.z;
            float zo = p0.w + p1.w + p2.w + p3.w + gv.w;
            float ff = fast_sigmoid(zf);
            float ii = fast_sigmoid(zi);
            float gg = fast_tanh(zg);
            float oo = fast_sigmoid(zo);
            cs = cs * ff + ii * gg;
            hn = fast_tanh(cs) * oo;
            if (!(w & 1)) hist[t][u] = hn;    // even wave of each pair writes
        }
        // no second barrier: next phase A readlanes source the OWN wave's
        // lanes 0..31; part[] is parity double-buffered.
    }
    __syncthreads();                          // hist read cross-wave below

    // Epilogue: out[b][t] = hist[t] . out_w + out_b, 16 threads per t.
    int tt = tid >> 4, j = tid & 15;
    const float4* hh = (const float4*)(&hist[tt][j * 8]);
    float4 a0q = hh[0], a1q = hh[1];
    const float* owp = out_w + j * 8;
    float pw = a0q.x * owp[0] + a0q.y * owp[1] + a0q.z * owp[2] + a0q.w * owp[3]
             + a1q.x * owp[4] + a1q.y * owp[5] + a1q.z * owp[6] + a1q.w * owp[7];
#pragma unroll
    for (int off = 8; off > 0; off >>= 1) pw += __shfl_down(pw, off, 16);
    if (j == 0) out[b * Tt + tt] = pw + out_b[0];
}

// ---------------------------------------------------------------------------
extern "C" void kernel_launch(void* const* d_in, const int* in_sizes, int n_in,
                              void* d_out, int out_size, void* d_ws, size_t ws_size,
                              hipStream_t stream) {
    const float* x   = (const float*)d_in[0];
    const float* w1  = (const float*)d_in[1];
    const float* b1  = (const float*)d_in[2];
    const float* w2  = (const float*)d_in[3];
    const float* b2  = (const float*)d_in[4];
    const float* Wf  = (const float*)d_in[5];
    const float* bf  = (const float*)d_in[6];
    const float* Wi  = (const float*)d_in[7];
    const float* bi  = (const float*)d_in[8];
    const float* Wc  = (const float*)d_in[9];
    const float* bc  = (const float*)d_in[10];
    const float* Wo  = (const float*)d_in[11];
    const float* bo  = (const float*)d_in[12];
    const float* ow  = (const float*)d_in[13];
    const float* ob  = (const float*)d_in[14];
    float* out = (float*)d_out;

    float* G = (float*)d_ws;                  // 256*512 = 131072 floats

    convfeat_kernel<<<Bb * Tt, 256, 0, stream>>>(x, w1, b1, w2, b2,
                                                 Wf, bf, Wi, bi, Wc, bc, Wo, bo, G);
    lstm_kernel<<<Bb, 512, 0, stream>>>(G, Wf, Wi, Wc, Wo, ow, ob, out);
}